// Round 1
// baseline (542.111 us; speedup 1.0000x reference)
//
#include <hip/hip_runtime.h>
#include <stdint.h>

#define DEVI __device__ __forceinline__

typedef __attribute__((ext_vector_type(8))) __bf16 bf16x8;
typedef __attribute__((ext_vector_type(4))) float f32x4;
typedef __attribute__((ext_vector_type(4))) unsigned short u16x4;
typedef unsigned short u16;

constexpr int Bn = 4, Sn = 2048, Dn = 1024, Hn = 16;
constexpr int Mn = Bn * Sn;                               // 8192
constexpr float QSCALE = 1.4426950408889634f / 32.0f;     // log2(e)/sqrt(D): folds softmax scale + exp2 base

// ---------- helpers ----------
DEVI u16 f2bf(float f) {                                  // RNE f32 -> bf16 bits
  uint32_t u = __builtin_bit_cast(uint32_t, f);
  u += 0x7fffu + ((u >> 16) & 1u);
  return (u16)(u >> 16);
}

typedef __attribute__((address_space(1))) void gvoid;
typedef __attribute__((address_space(3))) void lvoid;
DEVI void gload_lds16(const void* g, void* l) {
  // LDS dest is wave-uniform base + lane*16 (pass base only)
  __builtin_amdgcn_global_load_lds((gvoid*)(uintptr_t)g,
                                   (lvoid*)(uint32_t)(uintptr_t)l, 16, 0, 0);
}

DEVI f32x4 mfma16(bf16x8 a, bf16x8 b, f32x4 c) {
  return __builtin_amdgcn_mfma_f32_16x16x32_bf16(a, b, c, 0, 0, 0);
}

// ---------- cast fp32 -> bf16 ----------
struct CastArgs {
  const float* src[7];
  u16* dst[7];
  int n[7];
};

__global__ __launch_bounds__(256) void cast_kernel(CastArgs a) {
  const int seg = blockIdx.y;
  const float* __restrict__ src = a.src[seg];
  u16* __restrict__ dst = a.dst[seg];
  const int n = a.n[seg];
  const int stride = gridDim.x * 256 * 4;
  for (int i = (blockIdx.x * 256 + threadIdx.x) * 4; i < n; i += stride) {
    const float4 v = *reinterpret_cast<const float4*>(src + i);
    u16x4 p;
    p[0] = f2bf(v.x); p[1] = f2bf(v.y); p[2] = f2bf(v.z); p[3] = f2bf(v.w);
    *reinterpret_cast<u16x4*>(dst + i) = p;
  }
}

// ---------- GEMM: C[m][n] = sum_k A[m][k]*Bt[n][k] + bias[n] ----------
// MODE 0: Q out, bf16 [B][H][S][64], scaled by QSCALE
// MODE 1: K out, bf16 [B][H][S][64]
// MODE 2: V out, bf16 [B][H][64][S]  (transposed for PV B-fragments)
// MODE 3: fp32 out [M][N]
template <int MODE>
__global__ __launch_bounds__(256)
void gemm_bt(const u16* __restrict__ A, const u16* __restrict__ Bt,
             const float* __restrict__ bias, void* __restrict__ out) {
  constexpr int BK = 32, Kd = 1024;
  __shared__ __align__(16) u16 As[128 * BK];   // 8 KB
  __shared__ __align__(16) u16 Bs[128 * BK];   // 8 KB

  const int tid = threadIdx.x;
  const int lane = tid & 63;
  const int w = tid >> 6;             // 4 waves, 2x2
  const int wr = w >> 1, wc = w & 1;
  const int mt = blockIdx.x >> 3, nt = blockIdx.x & 7;   // 64 x 8 tiles
  const int m0 = mt * 128, n0 = nt * 128;
  const int c = lane & 15, g = lane >> 4;

  f32x4 acc[4][4] = {};

  // staging: chunk = (i*4+w)*64 + lane -> row = chunk>>2, col8 = (chunk&3)*8
  const u16* aA[2];
  const u16* aB[2];
  int loff[2];
  #pragma unroll
  for (int i = 0; i < 2; ++i) {
    const int chunk = (i * 4 + w) * 64 + lane;
    const int row = chunk >> 2, col = (chunk & 3) * 8;
    aA[i] = A + (size_t)(m0 + row) * Kd + col;
    aB[i] = Bt + (size_t)(n0 + row) * Kd + col;
    loff[i] = (i * 4 + w) * 1024;     // bytes
  }

  for (int kt = 0; kt < Kd; kt += BK) {
    #pragma unroll
    for (int i = 0; i < 2; ++i) {
      gload_lds16(aA[i] + kt, (char*)As + loff[i]);
      gload_lds16(aB[i] + kt, (char*)Bs + loff[i]);
    }
    __syncthreads();                  // drains vmcnt before barrier
    bf16x8 af[4], bfr[4];
    #pragma unroll
    for (int i = 0; i < 4; ++i) {
      af[i]  = *(const bf16x8*)(As + (wr * 64 + i * 16 + c) * BK + g * 8);
      bfr[i] = *(const bf16x8*)(Bs + (wc * 64 + i * 16 + c) * BK + g * 8);
    }
    #pragma unroll
    for (int mi = 0; mi < 4; ++mi)
      #pragma unroll
      for (int ni = 0; ni < 4; ++ni)
        acc[mi][ni] = mfma16(af[mi], bfr[ni], acc[mi][ni]);
    __syncthreads();                  // all reads done before next stage
  }

  // epilogue; C/D layout: col = lane&15, row = (lane>>4)*4 + reg
  #pragma unroll
  for (int mi = 0; mi < 4; ++mi) {
    #pragma unroll
    for (int ni = 0; ni < 4; ++ni) {
      const int n = n0 + wc * 64 + ni * 16 + c;
      const float bv = bias[n];
      const int mb = m0 + wr * 64 + mi * 16 + g * 4;
      const f32x4 v = acc[mi][ni];
      if constexpr (MODE == 0 || MODE == 1) {
        u16* dst = (u16*)out;
        const int h = n >> 6, hd = n & 63;
        #pragma unroll
        for (int j = 0; j < 4; ++j) {
          const int m = mb + j;
          const int b = m >> 11, s = m & 2047;
          float val = v[j] + bv;
          if constexpr (MODE == 0) val *= QSCALE;
          dst[(((size_t)(b * Hn + h) * Sn + s) << 6) + hd] = f2bf(val);
        }
      } else if constexpr (MODE == 2) {
        u16* dst = (u16*)out;
        const int h = n >> 6, hd = n & 63;
        const int b = mb >> 11, s = mb & 2047;   // 4 consecutive s, same b
        u16x4 pk;
        #pragma unroll
        for (int j = 0; j < 4; ++j) pk[j] = f2bf(v[j] + bv);
        *(u16x4*)(dst + ((size_t)((b * Hn + h) * 64 + hd)) * Sn + s) = pk;
      } else {
        float* dst = (float*)out;
        #pragma unroll
        for (int j = 0; j < 4; ++j)
          dst[(size_t)(mb + j) * Dn + n] = v[j] + bv;
      }
    }
  }
}

// ---------- flash attention ----------
// Q [B*H][S][64] (prescaled by QSCALE), K [B*H][S][64], Vt [B*H][64][S]
// X out bf16 [B][S][D] (heads merged). Grid: B*H*(S/128), 4 waves/block,
// each wave owns 32 q rows independently (no cross-wave sync).
__global__ __launch_bounds__(256)
void flash_attn(const u16* __restrict__ Q, const u16* __restrict__ K,
                const u16* __restrict__ Vt, u16* __restrict__ X) {
  __shared__ __align__(16) u16 Plds[4][32][72];   // pad 64->72: 16B-aligned rows, bank-spread

  const int tid = threadIdx.x, lane = tid & 63, w = tid >> 6;
  const int bh = blockIdx.x >> 4, qt = blockIdx.x & 15;
  const int b = bh >> 4, h = bh & 15;
  const int q0 = qt * 128 + w * 32;
  const int c = lane & 15, g = lane >> 4;

  const u16* Qb = Q + (size_t)bh * Sn * 64;
  const u16* Kb = K + (size_t)bh * Sn * 64;
  const u16* Vb = Vt + (size_t)bh * 64 * Sn;

  bf16x8 qf[2][2];
  #pragma unroll
  for (int qi = 0; qi < 2; ++qi)
    #pragma unroll
    for (int ks = 0; ks < 2; ++ks)
      qf[qi][ks] = *(const bf16x8*)(Qb + (size_t)(q0 + qi * 16 + c) * 64 + ks * 32 + g * 8);

  f32x4 o[2][4] = {};
  float mr[2][4], lr[2][4];
  #pragma unroll
  for (int qi = 0; qi < 2; ++qi)
    #pragma unroll
    for (int j = 0; j < 4; ++j) { mr[qi][j] = -3.0e38f; lr[qi][j] = 0.f; }

  for (int kv = 0; kv < Sn; kv += 64) {
    // S tile 32(q) x 64(k): D layout row=q=(g*4+j), col=key=(nf*16+c)
    f32x4 sc[2][4] = {};
    #pragma unroll
    for (int nf = 0; nf < 4; ++nf)
      #pragma unroll
      for (int ks = 0; ks < 2; ++ks) {
        const bf16x8 kf = *(const bf16x8*)(Kb + (size_t)(kv + nf * 16 + c) * 64 + ks * 32 + g * 8);
        sc[0][nf] = mfma16(qf[0][ks], kf, sc[0][nf]);
        sc[1][nf] = mfma16(qf[1][ks], kf, sc[1][nf]);
      }
    // online softmax (base-2; scale folded into Q)
    #pragma unroll
    for (int qi = 0; qi < 2; ++qi)
      #pragma unroll
      for (int j = 0; j < 4; ++j) {
        float t = fmaxf(fmaxf(sc[qi][0][j], sc[qi][1][j]),
                        fmaxf(sc[qi][2][j], sc[qi][3][j]));
        t = fmaxf(t, __shfl_xor(t, 1));
        t = fmaxf(t, __shfl_xor(t, 2));
        t = fmaxf(t, __shfl_xor(t, 4));
        t = fmaxf(t, __shfl_xor(t, 8));
        const float mnew = fmaxf(mr[qi][j], t);
        const float alpha = __builtin_exp2f(mr[qi][j] - mnew);
        mr[qi][j] = mnew;
        float ps = 0.f;
        #pragma unroll
        for (int nf = 0; nf < 4; ++nf) {
          const float p = __builtin_exp2f(sc[qi][nf][j] - mnew);
          sc[qi][nf][j] = p;
          ps += p;
        }
        ps += __shfl_xor(ps, 1); ps += __shfl_xor(ps, 2);
        ps += __shfl_xor(ps, 4); ps += __shfl_xor(ps, 8);
        lr[qi][j] = lr[qi][j] * alpha + ps;
        #pragma unroll
        for (int nd = 0; nd < 4; ++nd) o[qi][nd][j] *= alpha;
        #pragma unroll
        for (int nf = 0; nf < 4; ++nf)
          Plds[w][qi * 16 + g * 4 + j][nf * 16 + c] = f2bf(sc[qi][nf][j]);
      }
    // PV: O[32][64] += P[32][64] * V[64][64]
    #pragma unroll
    for (int ks2 = 0; ks2 < 2; ++ks2) {
      const bf16x8 pa0 = *(const bf16x8*)&Plds[w][c][ks2 * 32 + g * 8];
      const bf16x8 pa1 = *(const bf16x8*)&Plds[w][16 + c][ks2 * 32 + g * 8];
      #pragma unroll
      for (int nd = 0; nd < 4; ++nd) {
        const bf16x8 vf = *(const bf16x8*)(Vb + (size_t)(nd * 16 + c) * Sn + kv + ks2 * 32 + g * 8);
        o[0][nd] = mfma16(pa0, vf, o[0][nd]);
        o[1][nd] = mfma16(pa1, vf, o[1][nd]);
      }
    }
  }

  #pragma unroll
  for (int qi = 0; qi < 2; ++qi)
    #pragma unroll
    for (int j = 0; j < 4; ++j) {
      const float rn = 1.0f / lr[qi][j];
      const int s = q0 + qi * 16 + g * 4 + j;
      u16* dst = X + (size_t)(b * Sn + s) * Dn + h * 64 + c;
      #pragma unroll
      for (int nd = 0; nd < 4; ++nd)
        dst[nd * 16] = f2bf(o[qi][nd][j] * rn);
    }
}

// ---------- launch ----------
extern "C" void kernel_launch(void* const* d_in, const int* in_sizes, int n_in,
                              void* d_out, int out_size, void* d_ws, size_t ws_size,
                              hipStream_t stream) {
  (void)in_sizes; (void)n_in; (void)out_size; (void)ws_size;
  const float* query = (const float*)d_in[0];
  const float* key_  = (const float*)d_in[1];
  const float* value = (const float*)d_in[2];
  const float* Wq = (const float*)d_in[3];
  const float* bq = (const float*)d_in[4];
  const float* Wk = (const float*)d_in[5];
  const float* bk = (const float*)d_in[6];
  const float* Wv = (const float*)d_in[7];
  const float* bv = (const float*)d_in[8];
  const float* Wo = (const float*)d_in[9];
  const float* bo = (const float*)d_in[10];

  char* ws = (char*)d_ws;
  size_t off = 0;
  auto alloc = [&](size_t bytes) {
    void* p = ws + off;
    off += (bytes + 255) & ~(size_t)255;
    return p;
  };
  const size_t actB = (size_t)Mn * Dn * 2;   // 16 MB
  const size_t wB = (size_t)Dn * Dn * 2;     // 2 MB
  u16* qbuf = (u16*)alloc(actB);
  u16* kbuf = (u16*)alloc(actB);
  u16* vbuf = (u16*)alloc(actB);
  u16* wqb = (u16*)alloc(wB);
  u16* wkb = (u16*)alloc(wB);
  u16* wvb = (u16*)alloc(wB);
  u16* wob = (u16*)alloc(wB);
  u16* Qh = (u16*)alloc(actB);
  u16* Kh = (u16*)alloc(actB);
  u16* Vt = (u16*)alloc(actB);
  u16* Xb = qbuf;   // reuse: query_bf16 dead after Q projection

  CastArgs ca;
  ca.src[0] = query; ca.src[1] = key_; ca.src[2] = value;
  ca.src[3] = Wq; ca.src[4] = Wk; ca.src[5] = Wv; ca.src[6] = Wo;
  ca.dst[0] = qbuf; ca.dst[1] = kbuf; ca.dst[2] = vbuf;
  ca.dst[3] = wqb; ca.dst[4] = wkb; ca.dst[5] = wvb; ca.dst[6] = wob;
  ca.n[0] = ca.n[1] = ca.n[2] = Mn * Dn;
  ca.n[3] = ca.n[4] = ca.n[5] = ca.n[6] = Dn * Dn;
  cast_kernel<<<dim3(1024, 7), 256, 0, stream>>>(ca);

  gemm_bt<0><<<dim3(512), 256, 0, stream>>>(qbuf, wqb, bq, Qh);
  gemm_bt<1><<<dim3(512), 256, 0, stream>>>(kbuf, wkb, bk, Kh);
  gemm_bt<2><<<dim3(512), 256, 0, stream>>>(vbuf, wvb, bv, Vt);
  flash_attn<<<dim3(Bn * Hn * (Sn / 128)), 256, 0, stream>>>(Qh, Kh, Vt, Xb);
  gemm_bt<3><<<dim3(512), 256, 0, stream>>>(Xb, wob, bo, (float*)d_out);
}

// Round 2
// 381.026 us; speedup vs baseline: 1.4228x; 1.4228x over previous
//
#include <hip/hip_runtime.h>
#include <stdint.h>

#define DEVI __device__ __forceinline__

typedef __attribute__((ext_vector_type(8))) __bf16 bf16x8;
typedef __attribute__((ext_vector_type(4))) __bf16 bf16x4;
typedef __attribute__((ext_vector_type(4))) float f32x4;
typedef __attribute__((ext_vector_type(4))) unsigned short u16x4;
typedef unsigned short u16;

constexpr int Bn = 4, Sn = 2048, Dn = 1024, Hn = 16;
constexpr int Mn = Bn * Sn;                               // 8192
constexpr float QSCALE = 1.4426950408889634f / 32.0f;     // log2(e)/sqrt(D): folds softmax scale + exp2 base

// ---------- helpers ----------
DEVI u16 f2bf(float f) {                                  // RNE f32 -> bf16 bits
  uint32_t u = __builtin_bit_cast(uint32_t, f);
  u += 0x7fffu + ((u >> 16) & 1u);
  return (u16)(u >> 16);
}

typedef __attribute__((address_space(1))) void gvoid;
typedef __attribute__((address_space(3))) void lvoid;
DEVI void gload_lds16(const void* g, void* l) {
  // LDS dest is wave-uniform base + lane*16 (pass base only)
  __builtin_amdgcn_global_load_lds((gvoid*)(uintptr_t)g,
                                   (lvoid*)(uint32_t)(uintptr_t)l, 16, 0, 0);
}

DEVI f32x4 mfma16(bf16x8 a, bf16x8 b, f32x4 c) {
  return __builtin_amdgcn_mfma_f32_16x16x32_bf16(a, b, c, 0, 0, 0);
}

// ---------- cast fp32 -> bf16 ----------
struct CastArgs {
  const float* src[7];
  u16* dst[7];
  int n[7];
};

__global__ __launch_bounds__(256) void cast_kernel(CastArgs a) {
  const int seg = blockIdx.y;
  const float* __restrict__ src = a.src[seg];
  u16* __restrict__ dst = a.dst[seg];
  const int n = a.n[seg];
  const int stride = gridDim.x * 256 * 4;
  for (int i = (blockIdx.x * 256 + threadIdx.x) * 4; i < n; i += stride) {
    const float4 v = *reinterpret_cast<const float4*>(src + i);
    u16x4 p;
    p[0] = f2bf(v.x); p[1] = f2bf(v.y); p[2] = f2bf(v.z); p[3] = f2bf(v.w);
    *reinterpret_cast<u16x4*>(dst + i) = p;
  }
}

// ---------- GEMM: C[m][n] = sum_k A[m][k]*Bt[n][k] + bias[n] ----------
// MODE 0: Q out, bf16 [B][H][S][64], scaled by QSCALE
// MODE 1: K out, bf16 [B][H][S][64]
// MODE 2: V out, bf16 [B][H][64][S]  (transposed for PV B-fragments)
// MODE 3: fp32 out [M][N]
template <int MODE>
__global__ __launch_bounds__(256)
void gemm_bt(const u16* __restrict__ A, const u16* __restrict__ Bt,
             const float* __restrict__ bias, void* __restrict__ out) {
  constexpr int BK = 32, Kd = 1024;
  __shared__ __align__(16) u16 As[128 * BK];   // 8 KB
  __shared__ __align__(16) u16 Bs[128 * BK];   // 8 KB

  const int tid = threadIdx.x;
  const int lane = tid & 63;
  const int w = tid >> 6;             // 4 waves, 2x2
  const int wr = w >> 1, wc = w & 1;
  const int mt = blockIdx.x >> 3, nt = blockIdx.x & 7;   // 64 x 8 tiles
  const int m0 = mt * 128, n0 = nt * 128;
  const int c = lane & 15, g = lane >> 4;

  f32x4 acc[4][4] = {};

  // staging: chunk = (i*4+w)*64 + lane -> row = chunk>>2, col8 = (chunk&3)*8
  const u16* aA[2];
  const u16* aB[2];
  int loff[2];
  #pragma unroll
  for (int i = 0; i < 2; ++i) {
    const int chunk = (i * 4 + w) * 64 + lane;
    const int row = chunk >> 2, col = (chunk & 3) * 8;
    aA[i] = A + (size_t)(m0 + row) * Kd + col;
    aB[i] = Bt + (size_t)(n0 + row) * Kd + col;
    loff[i] = (i * 4 + w) * 1024;     // bytes
  }

  for (int kt = 0; kt < Kd; kt += BK) {
    #pragma unroll
    for (int i = 0; i < 2; ++i) {
      gload_lds16(aA[i] + kt, (char*)As + loff[i]);
      gload_lds16(aB[i] + kt, (char*)Bs + loff[i]);
    }
    __syncthreads();                  // drains vmcnt before barrier
    bf16x8 af[4], bfr[4];
    #pragma unroll
    for (int i = 0; i < 4; ++i) {
      af[i]  = *(const bf16x8*)(As + (wr * 64 + i * 16 + c) * BK + g * 8);
      bfr[i] = *(const bf16x8*)(Bs + (wc * 64 + i * 16 + c) * BK + g * 8);
    }
    #pragma unroll
    for (int mi = 0; mi < 4; ++mi)
      #pragma unroll
      for (int ni = 0; ni < 4; ++ni)
        acc[mi][ni] = mfma16(af[mi], bfr[ni], acc[mi][ni]);
    __syncthreads();                  // all reads done before next stage
  }

  // epilogue; C/D layout: col = lane&15, row = (lane>>4)*4 + reg
  #pragma unroll
  for (int mi = 0; mi < 4; ++mi) {
    #pragma unroll
    for (int ni = 0; ni < 4; ++ni) {
      const int n = n0 + wc * 64 + ni * 16 + c;
      const float bv = bias[n];
      const int mb = m0 + wr * 64 + mi * 16 + g * 4;
      const f32x4 v = acc[mi][ni];
      if constexpr (MODE == 0 || MODE == 1) {
        u16* dst = (u16*)out;
        const int h = n >> 6, hd = n & 63;
        #pragma unroll
        for (int j = 0; j < 4; ++j) {
          const int m = mb + j;
          const int b = m >> 11, s = m & 2047;
          float val = v[j] + bv;
          if constexpr (MODE == 0) val *= QSCALE;
          dst[(((size_t)(b * Hn + h) * Sn + s) << 6) + hd] = f2bf(val);
        }
      } else if constexpr (MODE == 2) {
        u16* dst = (u16*)out;
        const int h = n >> 6, hd = n & 63;
        const int b = mb >> 11, s = mb & 2047;   // 4 consecutive s, same b
        u16x4 pk;
        #pragma unroll
        for (int j = 0; j < 4; ++j) pk[j] = f2bf(v[j] + bv);
        *(u16x4*)(dst + ((size_t)((b * Hn + h) * 64 + hd)) * Sn + s) = pk;
      } else {
        float* dst = (float*)out;
        #pragma unroll
        for (int j = 0; j < 4; ++j)
          dst[(size_t)(mb + j) * Dn + n] = v[j] + bv;
      }
    }
  }
}

// ---------- flash attention (swapped QK^T: wave-local softmax) ----------
// Q [B*H][S][64] (prescaled by QSCALE), K [B*H][S][64], Vt [B*H][64][S]
// X out bf16 [B][S][D]. Grid: B*H*(S/128), 4 waves/block, 32 q-rows/wave.
// QK^T computed as mfma(K,Q): score frag has col=q (lane&15), row=k.
// Softmax per q is 15 in-lane ops + 2 shuffles. P packed to LDS as 8B writes,
// read back as 16B A-fragments for PV.
__global__ __launch_bounds__(256)
void flash_attn(const u16* __restrict__ Q, const u16* __restrict__ K,
                const u16* __restrict__ Vt, u16* __restrict__ X) {
  __shared__ __align__(16) u16 Plds[4][32][72];   // stride 144B: 16B-aligned, bank-even

  const int tid = threadIdx.x, lane = tid & 63, w = tid >> 6;
  const int bh = blockIdx.x >> 4, qt = blockIdx.x & 15;
  const int b = bh >> 4, h = bh & 15;
  const int q0 = qt * 128 + w * 32;
  const int c = lane & 15, g = lane >> 4;

  const u16* Qb = Q + (size_t)bh * Sn * 64;
  const u16* Kb = K + (size_t)bh * Sn * 64;
  const u16* Vb = Vt + (size_t)bh * 64 * Sn;

  // Q as B-operand fragments: lane (c,g) holds Q[q0+qf*16+c][ks*32+g*8 ..+7]
  bf16x8 qf[2][2];
  #pragma unroll
  for (int qi = 0; qi < 2; ++qi)
    #pragma unroll
    for (int ks = 0; ks < 2; ++ks)
      qf[qi][ks] = *(const bf16x8*)(Qb + (size_t)(q0 + qi * 16 + c) * 64 + ks * 32 + g * 8);

  f32x4 o[2][4] = {};
  float m2[2] = {-1.0e30f, -1.0e30f};   // running max for q = q0 + qi*16 + c
  float l2[2] = {0.f, 0.f};

  for (int kv = 0; kv < Sn; kv += 64) {
    // S^T tile: sc[qi][kf] = D with col=q=(qi*16+c), row=k=(kf*16+g*4+j)
    f32x4 sc[2][4] = {};
    #pragma unroll
    for (int kf = 0; kf < 4; ++kf)
      #pragma unroll
      for (int ks = 0; ks < 2; ++ks) {
        const bf16x8 kfr = *(const bf16x8*)(Kb + (size_t)(kv + kf * 16 + c) * 64 + ks * 32 + g * 8);
        sc[0][kf] = mfma16(kfr, qf[0][ks], sc[0][kf]);
        sc[1][kf] = mfma16(kfr, qf[1][ks], sc[1][kf]);
      }

    // per-q max: 16 in-lane values, then reduce across the 4 g-groups
    float mx[2], ps[2];
    #pragma unroll
    for (int qi = 0; qi < 2; ++qi) {
      float t0 = fmaxf(fmaxf(sc[qi][0][0], sc[qi][0][1]), fmaxf(sc[qi][0][2], sc[qi][0][3]));
      float t1 = fmaxf(fmaxf(sc[qi][1][0], sc[qi][1][1]), fmaxf(sc[qi][1][2], sc[qi][1][3]));
      float t2 = fmaxf(fmaxf(sc[qi][2][0], sc[qi][2][1]), fmaxf(sc[qi][2][2], sc[qi][2][3]));
      float t3 = fmaxf(fmaxf(sc[qi][3][0], sc[qi][3][1]), fmaxf(sc[qi][3][2], sc[qi][3][3]));
      float t = fmaxf(fmaxf(t0, t1), fmaxf(t2, t3));
      t = fmaxf(t, __shfl_xor(t, 16));
      t = fmaxf(t, __shfl_xor(t, 32));
      mx[qi] = t;
    }

    // T13 defer-max: skip O-rescale when max growth is small (P <= 2^8, safe)
    const float growth = fmaxf(mx[0] - m2[0], mx[1] - m2[1]);
    if (!__all(growth <= 8.0f)) {
      float alpha[2];
      #pragma unroll
      for (int qi = 0; qi < 2; ++qi) {
        const float mnew = fmaxf(m2[qi], mx[qi]);
        alpha[qi] = __builtin_exp2f(m2[qi] - mnew);
        m2[qi] = mnew;
        l2[qi] *= alpha[qi];
      }
      // transpose alpha to O layout (q = qi*16 + g*4 + j) and rescale
      #pragma unroll
      for (int qi = 0; qi < 2; ++qi) {
        #pragma unroll
        for (int j = 0; j < 4; ++j) {
          const float aj = __shfl(alpha[qi], 4 * g + j);
          #pragma unroll
          for (int nd = 0; nd < 4; ++nd) o[qi][nd][j] *= aj;
        }
      }
    }

    // P = exp2(S - m), row-sum, pack to bf16, write LDS (8B vectorized)
    #pragma unroll
    for (int qi = 0; qi < 2; ++qi) {
      float s = 0.f;
      #pragma unroll
      for (int kf = 0; kf < 4; ++kf) {
        bf16x4 pk;
        #pragma unroll
        for (int j = 0; j < 4; ++j) {
          const float p = __builtin_exp2f(sc[qi][kf][j] - m2[qi]);
          s += p;
          pk[j] = (__bf16)p;
        }
        *(bf16x4*)&Plds[w][qi * 16 + c][kf * 16 + g * 4] = pk;
      }
      s += __shfl_xor(s, 16);
      s += __shfl_xor(s, 32);
      l2[qi] += s;
    }

    // PV: O[32][64] += P[32][64] * V[64][64]
    #pragma unroll
    for (int ks2 = 0; ks2 < 2; ++ks2) {
      const bf16x8 pa0 = *(const bf16x8*)&Plds[w][c][ks2 * 32 + g * 8];
      const bf16x8 pa1 = *(const bf16x8*)&Plds[w][16 + c][ks2 * 32 + g * 8];
      #pragma unroll
      for (int nd = 0; nd < 4; ++nd) {
        const bf16x8 vf = *(const bf16x8*)(Vb + (size_t)(nd * 16 + c) * Sn + kv + ks2 * 32 + g * 8);
        o[0][nd] = mfma16(pa0, vf, o[0][nd]);
        o[1][nd] = mfma16(pa1, vf, o[1][nd]);
      }
    }
  }

  // epilogue: transpose 1/l to O layout, normalize, store
  #pragma unroll
  for (int qi = 0; qi < 2; ++qi) {
    const float rl = 1.0f / l2[qi];
    #pragma unroll
    for (int j = 0; j < 4; ++j) {
      const float rn = __shfl(rl, 4 * g + j);
      const int s = q0 + qi * 16 + g * 4 + j;
      u16* dst = X + (size_t)(b * Sn + s) * Dn + h * 64 + c;
      #pragma unroll
      for (int nd = 0; nd < 4; ++nd)
        dst[nd * 16] = f2bf(o[qi][nd][j] * rn);
    }
  }
}

// ---------- launch ----------
extern "C" void kernel_launch(void* const* d_in, const int* in_sizes, int n_in,
                              void* d_out, int out_size, void* d_ws, size_t ws_size,
                              hipStream_t stream) {
  (void)in_sizes; (void)n_in; (void)out_size; (void)ws_size;
  const float* query = (const float*)d_in[0];
  const float* key_  = (const float*)d_in[1];
  const float* value = (const float*)d_in[2];
  const float* Wq = (const float*)d_in[3];
  const float* bq = (const float*)d_in[4];
  const float* Wk = (const float*)d_in[5];
  const float* bk = (const float*)d_in[6];
  const float* Wv = (const float*)d_in[7];
  const float* bv = (const float*)d_in[8];
  const float* Wo = (const float*)d_in[9];
  const float* bo = (const float*)d_in[10];

  char* ws = (char*)d_ws;
  size_t off = 0;
  auto alloc = [&](size_t bytes) {
    void* p = ws + off;
    off += (bytes + 255) & ~(size_t)255;
    return p;
  };
  const size_t actB = (size_t)Mn * Dn * 2;   // 16 MB
  const size_t wB = (size_t)Dn * Dn * 2;     // 2 MB
  u16* qbuf = (u16*)alloc(actB);
  u16* kbuf = (u16*)alloc(actB);
  u16* vbuf = (u16*)alloc(actB);
  u16* wqb = (u16*)alloc(wB);
  u16* wkb = (u16*)alloc(wB);
  u16* wvb = (u16*)alloc(wB);
  u16* wob = (u16*)alloc(wB);
  u16* Qh = (u16*)alloc(actB);
  u16* Kh = (u16*)alloc(actB);
  u16* Vt = (u16*)alloc(actB);
  u16* Xb = qbuf;   // reuse: query_bf16 dead after Q projection

  CastArgs ca;
  ca.src[0] = query; ca.src[1] = key_; ca.src[2] = value;
  ca.src[3] = Wq; ca.src[4] = Wk; ca.src[5] = Wv; ca.src[6] = Wo;
  ca.dst[0] = qbuf; ca.dst[1] = kbuf; ca.dst[2] = vbuf;
  ca.dst[3] = wqb; ca.dst[4] = wkb; ca.dst[5] = wvb; ca.dst[6] = wob;
  ca.n[0] = ca.n[1] = ca.n[2] = Mn * Dn;
  ca.n[3] = ca.n[4] = ca.n[5] = ca.n[6] = Dn * Dn;
  cast_kernel<<<dim3(1024, 7), 256, 0, stream>>>(ca);

  gemm_bt<0><<<dim3(512), 256, 0, stream>>>(qbuf, wqb, bq, Qh);
  gemm_bt<1><<<dim3(512), 256, 0, stream>>>(kbuf, wkb, bk, Kh);
  gemm_bt<2><<<dim3(512), 256, 0, stream>>>(vbuf, wvb, bv, Vt);
  flash_attn<<<dim3(Bn * Hn * (Sn / 128)), 256, 0, stream>>>(Qh, Kh, Vt, Xb);
  gemm_bt<3><<<dim3(512), 256, 0, stream>>>(Xb, wob, bo, (float*)d_out);
}

// Round 3
// 379.130 us; speedup vs baseline: 1.4299x; 1.0050x over previous
//
#include <hip/hip_runtime.h>
#include <stdint.h>

#define DEVI __device__ __forceinline__

typedef __attribute__((ext_vector_type(8))) __bf16 bf16x8;
typedef __attribute__((ext_vector_type(4))) __bf16 bf16x4;
typedef __attribute__((ext_vector_type(4))) float f32x4;
typedef __attribute__((ext_vector_type(4))) unsigned short u16x4;
typedef unsigned short u16;

constexpr int Bn = 4, Sn = 2048, Dn = 1024, Hn = 16;
constexpr int Mn = Bn * Sn;                               // 8192
constexpr float QSCALE = 1.4426950408889634f / 32.0f;     // log2(e)/sqrt(D): folds softmax scale + exp2 base

// ---------- helpers ----------
DEVI u16 f2bf(float f) {                                  // RNE f32 -> bf16 bits
  uint32_t u = __builtin_bit_cast(uint32_t, f);
  u += 0x7fffu + ((u >> 16) & 1u);
  return (u16)(u >> 16);
}

typedef __attribute__((address_space(1))) void gvoid;
typedef __attribute__((address_space(3))) void lvoid;
DEVI void gload_lds16(const void* g, void* l) {
  // LDS dest is wave-uniform base + lane*16 (pass base only)
  __builtin_amdgcn_global_load_lds((gvoid*)(uintptr_t)g,
                                   (lvoid*)(uint32_t)(uintptr_t)l, 16, 0, 0);
}

DEVI f32x4 mfma16(bf16x8 a, bf16x8 b, f32x4 c) {
  return __builtin_amdgcn_mfma_f32_16x16x32_bf16(a, b, c, 0, 0, 0);
}

// ---------- cast fp32 -> bf16 ----------
struct CastArgs {
  const float* src[7];
  u16* dst[7];
  int n[7];
};

__global__ __launch_bounds__(256) void cast_kernel(CastArgs a) {
  const int seg = blockIdx.y;
  const float* __restrict__ src = a.src[seg];
  u16* __restrict__ dst = a.dst[seg];
  const int n = a.n[seg];
  const int stride = gridDim.x * 256 * 4;
  for (int i = (blockIdx.x * 256 + threadIdx.x) * 4; i < n; i += stride) {
    const float4 v = *reinterpret_cast<const float4*>(src + i);
    u16x4 p;
    p[0] = f2bf(v.x); p[1] = f2bf(v.y); p[2] = f2bf(v.z); p[3] = f2bf(v.w);
    *reinterpret_cast<u16x4*>(dst + i) = p;
  }
}

// ---------- GEMM: C[m][n] = sum_k A[m][k]*Bt[n][k] + bias[n] ----------
// MODE 0: Q out, bf16 [B][H][S][64], scaled by QSCALE
// MODE 1: K out, bf16 [B][H][S][64]
// MODE 2: V out, bf16 [B][H][64][S]  (transposed for PV B-fragments)
// MODE 3: fp32 out [M][N]
template <int MODE>
__global__ __launch_bounds__(256)
void gemm_bt(const u16* __restrict__ A, const u16* __restrict__ Bt,
             const float* __restrict__ bias, void* __restrict__ out) {
  constexpr int BK = 32, Kd = 1024;
  __shared__ __align__(16) u16 As[128 * BK];   // 8 KB
  __shared__ __align__(16) u16 Bs[128 * BK];   // 8 KB

  const int tid = threadIdx.x;
  const int lane = tid & 63;
  const int w = tid >> 6;             // 4 waves, 2x2
  const int wr = w >> 1, wc = w & 1;
  const int mt = blockIdx.x >> 3, nt = blockIdx.x & 7;   // 64 x 8 tiles
  const int m0 = mt * 128, n0 = nt * 128;
  const int c = lane & 15, g = lane >> 4;

  f32x4 acc[4][4] = {};

  // staging: chunk = (i*4+w)*64 + lane -> row = chunk>>2, col8 = (chunk&3)*8
  const u16* aA[2];
  const u16* aB[2];
  int loff[2];
  #pragma unroll
  for (int i = 0; i < 2; ++i) {
    const int chunk = (i * 4 + w) * 64 + lane;
    const int row = chunk >> 2, col = (chunk & 3) * 8;
    aA[i] = A + (size_t)(m0 + row) * Kd + col;
    aB[i] = Bt + (size_t)(n0 + row) * Kd + col;
    loff[i] = (i * 4 + w) * 1024;     // bytes
  }

  for (int kt = 0; kt < Kd; kt += BK) {
    #pragma unroll
    for (int i = 0; i < 2; ++i) {
      gload_lds16(aA[i] + kt, (char*)As + loff[i]);
      gload_lds16(aB[i] + kt, (char*)Bs + loff[i]);
    }
    __syncthreads();                  // drains vmcnt before barrier
    bf16x8 af[4], bfr[4];
    #pragma unroll
    for (int i = 0; i < 4; ++i) {
      af[i]  = *(const bf16x8*)(As + (wr * 64 + i * 16 + c) * BK + g * 8);
      bfr[i] = *(const bf16x8*)(Bs + (wc * 64 + i * 16 + c) * BK + g * 8);
    }
    #pragma unroll
    for (int mi = 0; mi < 4; ++mi)
      #pragma unroll
      for (int ni = 0; ni < 4; ++ni)
        acc[mi][ni] = mfma16(af[mi], bfr[ni], acc[mi][ni]);
    __syncthreads();                  // all reads done before next stage
  }

  // epilogue; C/D layout: col = lane&15, row = (lane>>4)*4 + reg
  #pragma unroll
  for (int mi = 0; mi < 4; ++mi) {
    #pragma unroll
    for (int ni = 0; ni < 4; ++ni) {
      const int n = n0 + wc * 64 + ni * 16 + c;
      const float bv = bias[n];
      const int mb = m0 + wr * 64 + mi * 16 + g * 4;
      const f32x4 v = acc[mi][ni];
      if constexpr (MODE == 0 || MODE == 1) {
        u16* dst = (u16*)out;
        const int h = n >> 6, hd = n & 63;
        #pragma unroll
        for (int j = 0; j < 4; ++j) {
          const int m = mb + j;
          const int b = m >> 11, s = m & 2047;
          float val = v[j] + bv;
          if constexpr (MODE == 0) val *= QSCALE;
          dst[(((size_t)(b * Hn + h) * Sn + s) << 6) + hd] = f2bf(val);
        }
      } else if constexpr (MODE == 2) {
        u16* dst = (u16*)out;
        const int h = n >> 6, hd = n & 63;
        const int b = mb >> 11, s = mb & 2047;   // 4 consecutive s, same b
        u16x4 pk;
        #pragma unroll
        for (int j = 0; j < 4; ++j) pk[j] = f2bf(v[j] + bv);
        *(u16x4*)(dst + ((size_t)((b * Hn + h) * 64 + hd)) * Sn + s) = pk;
      } else {
        float* dst = (float*)out;
        #pragma unroll
        for (int j = 0; j < 4; ++j)
          dst[(size_t)(mb + j) * Dn + n] = v[j] + bv;
      }
    }
  }
}

// ---------- flash attention (swapped QK^T + cross-tile register prefetch) ----------
// Q [B*H][S][64] (prescaled by QSCALE), K [B*H][S][64], Vt [B*H][64][S]
// X out bf16 [B][S][D]. Grid: 1024 blocks; bid = qt*64 + bh so the 16 q-tile
// blocks of one (b,h) land on the same XCD (hardware round-robins bid%8).
// 4 independent waves/block, 32 q-rows/wave.
// Pipeline: K(t+1) loads issue right after QK^T(t) (hidden under softmax+PV);
// V(t+1) loads issue after PV(t) (hidden under next QK^T+softmax).
__global__ __launch_bounds__(256)
void flash_attn(const u16* __restrict__ Q, const u16* __restrict__ K,
                const u16* __restrict__ Vt, u16* __restrict__ X) {
  // P staged in PV-A-fragment order: read is ds_read_b128 at lane*16B (0-conflict)
  __shared__ __align__(16) u16 Plds[4][2][2][64 * 8];   // 16 KB

  const int tid = threadIdx.x, lane = tid & 63, w = tid >> 6;
  const int bid = blockIdx.x;
  const int bh = bid & 63, qt = bid >> 6;
  const int b = bh >> 4, h = bh & 15;
  const int q0 = qt * 128 + w * 32;
  const int c = lane & 15, g = lane >> 4;

  const u16* Qb = Q + (size_t)bh * Sn * 64;
  const u16* Kb = K + (size_t)bh * Sn * 64;
  const u16* Vb = Vt + (size_t)bh * 64 * Sn;

  // Q as B-operand fragments: lane (c,g) holds Q[q0+qi*16+c][ks*32+g*8 ..+7]
  bf16x8 qf[2][2];
  #pragma unroll
  for (int qi = 0; qi < 2; ++qi)
    #pragma unroll
    for (int ks = 0; ks < 2; ++ks)
      qf[qi][ks] = *(const bf16x8*)(Qb + (size_t)(q0 + qi * 16 + c) * 64 + ks * 32 + g * 8);

  bf16x8 kfr[4][2];   // K-fragments, current tile (prefetched)
  bf16x8 vf[4][2];    // V-fragments, current tile (prefetched)
  auto loadK = [&](int kv_) {
    #pragma unroll
    for (int kf = 0; kf < 4; ++kf)
      #pragma unroll
      for (int ks = 0; ks < 2; ++ks)
        kfr[kf][ks] = *(const bf16x8*)(Kb + (size_t)(kv_ + kf * 16 + c) * 64 + ks * 32 + g * 8);
  };
  auto loadV = [&](int kv_) {
    #pragma unroll
    for (int nd = 0; nd < 4; ++nd)
      #pragma unroll
      for (int ks2 = 0; ks2 < 2; ++ks2)
        vf[nd][ks2] = *(const bf16x8*)(Vb + (size_t)(nd * 16 + c) * Sn + kv_ + ks2 * 32 + g * 8);
  };

  loadK(0);
  loadV(0);

  f32x4 o[2][4] = {};
  float m2[2] = {-1.0e30f, -1.0e30f};   // running max for q = q0 + qi*16 + c
  float l2[2] = {0.f, 0.f};

  for (int kv = 0; kv < Sn; kv += 64) {
    const int kvn = (kv + 64) & (Sn - 1);   // last-iter prefetch wraps (unused, in-bounds)

    // S^T tile: sc[qi][kf] = D with col=q=(qi*16+c), row=k=(kf*16+g*4+j)
    f32x4 sc[2][4] = {};
    __builtin_amdgcn_s_setprio(1);
    #pragma unroll
    for (int kf = 0; kf < 4; ++kf)
      #pragma unroll
      for (int ks = 0; ks < 2; ++ks) {
        sc[0][kf] = mfma16(kfr[kf][ks], qf[0][ks], sc[0][kf]);
        sc[1][kf] = mfma16(kfr[kf][ks], qf[1][ks], sc[1][kf]);
      }
    __builtin_amdgcn_s_setprio(0);

    loadK(kvn);   // prefetch next K: in flight during softmax + PV

    // per-q max: 16 in-lane values, then reduce across the 4 g-groups
    float mx[2];
    #pragma unroll
    for (int qi = 0; qi < 2; ++qi) {
      float t0 = fmaxf(fmaxf(sc[qi][0][0], sc[qi][0][1]), fmaxf(sc[qi][0][2], sc[qi][0][3]));
      float t1 = fmaxf(fmaxf(sc[qi][1][0], sc[qi][1][1]), fmaxf(sc[qi][1][2], sc[qi][1][3]));
      float t2 = fmaxf(fmaxf(sc[qi][2][0], sc[qi][2][1]), fmaxf(sc[qi][2][2], sc[qi][2][3]));
      float t3 = fmaxf(fmaxf(sc[qi][3][0], sc[qi][3][1]), fmaxf(sc[qi][3][2], sc[qi][3][3]));
      float t = fmaxf(fmaxf(t0, t1), fmaxf(t2, t3));
      t = fmaxf(t, __shfl_xor(t, 16));
      t = fmaxf(t, __shfl_xor(t, 32));
      mx[qi] = t;
    }

    // T13 defer-max: skip O-rescale when max growth is small (P <= 2^8, safe)
    const float growth = fmaxf(mx[0] - m2[0], mx[1] - m2[1]);
    if (!__all(growth <= 8.0f)) {
      float alpha[2];
      #pragma unroll
      for (int qi = 0; qi < 2; ++qi) {
        const float mnew = fmaxf(m2[qi], mx[qi]);
        alpha[qi] = __builtin_exp2f(m2[qi] - mnew);
        m2[qi] = mnew;
        l2[qi] *= alpha[qi];
      }
      // transpose alpha to O layout (q = qi*16 + g*4 + j) and rescale
      #pragma unroll
      for (int qi = 0; qi < 2; ++qi) {
        #pragma unroll
        for (int j = 0; j < 4; ++j) {
          const float aj = __shfl(alpha[qi], 4 * g + j);
          #pragma unroll
          for (int nd = 0; nd < 4; ++nd) o[qi][nd][j] *= aj;
        }
      }
    }

    // P = exp2(S - m), row-sum, pack to bf16, write LDS in A-frag order.
    // Value at lane (c,g) reg j of frag (qi,kf) is P[q=qi*16+c][k=kf*16+g*4+j];
    // dest frag (qi, ks2=kf>>1), dest lane-slot = ((kf&1)*2+(g>>1))*16 + c,
    // dest byte offset = (g&1)*8.
    #pragma unroll
    for (int qi = 0; qi < 2; ++qi) {
      float s = 0.f;
      #pragma unroll
      for (int kf = 0; kf < 4; ++kf) {
        bf16x4 pk;
        #pragma unroll
        for (int j = 0; j < 4; ++j) {
          const float p = __builtin_exp2f(sc[qi][kf][j] - m2[qi]);
          s += p;
          pk[j] = (__bf16)p;
        }
        const int gp = (kf & 1) * 2 + (g >> 1);
        *(bf16x4*)&Plds[w][qi][kf >> 1][(gp * 16 + c) * 8 + (g & 1) * 4] = pk;
      }
      s += __shfl_xor(s, 16);
      s += __shfl_xor(s, 32);
      l2[qi] += s;
    }

    // PV: O[32][64] += P[32][64] * V[64][64]; A-frag read is linear lane*16B
    #pragma unroll
    for (int ks2 = 0; ks2 < 2; ++ks2) {
      const bf16x8 pa0 = *(const bf16x8*)&Plds[w][0][ks2][lane * 8];
      const bf16x8 pa1 = *(const bf16x8*)&Plds[w][1][ks2][lane * 8];
      __builtin_amdgcn_s_setprio(1);
      #pragma unroll
      for (int nd = 0; nd < 4; ++nd) {
        o[0][nd] = mfma16(pa0, vf[nd][ks2], o[0][nd]);
        o[1][nd] = mfma16(pa1, vf[nd][ks2], o[1][nd]);
      }
      __builtin_amdgcn_s_setprio(0);
    }

    loadV(kvn);   // prefetch next V: in flight during next QK^T + softmax
  }

  // epilogue: transpose 1/l to O layout, normalize, store
  #pragma unroll
  for (int qi = 0; qi < 2; ++qi) {
    const float rl = 1.0f / l2[qi];
    #pragma unroll
    for (int j = 0; j < 4; ++j) {
      const float rn = __shfl(rl, 4 * g + j);
      const int s = q0 + qi * 16 + g * 4 + j;
      u16* dst = X + (size_t)(b * Sn + s) * Dn + h * 64 + c;
      #pragma unroll
      for (int nd = 0; nd < 4; ++nd)
        dst[nd * 16] = f2bf(o[qi][nd][j] * rn);
    }
  }
}

// ---------- launch ----------
extern "C" void kernel_launch(void* const* d_in, const int* in_sizes, int n_in,
                              void* d_out, int out_size, void* d_ws, size_t ws_size,
                              hipStream_t stream) {
  (void)in_sizes; (void)n_in; (void)out_size; (void)ws_size;
  const float* query = (const float*)d_in[0];
  const float* key_  = (const float*)d_in[1];
  const float* value = (const float*)d_in[2];
  const float* Wq = (const float*)d_in[3];
  const float* bq = (const float*)d_in[4];
  const float* Wk = (const float*)d_in[5];
  const float* bk = (const float*)d_in[6];
  const float* Wv = (const float*)d_in[7];
  const float* bv = (const float*)d_in[8];
  const float* Wo = (const float*)d_in[9];
  const float* bo = (const float*)d_in[10];

  char* ws = (char*)d_ws;
  size_t off = 0;
  auto alloc = [&](size_t bytes) {
    void* p = ws + off;
    off += (bytes + 255) & ~(size_t)255;
    return p;
  };
  const size_t actB = (size_t)Mn * Dn * 2;   // 16 MB
  const size_t wB = (size_t)Dn * Dn * 2;     // 2 MB
  u16* qbuf = (u16*)alloc(actB);
  u16* kbuf = (u16*)alloc(actB);
  u16* vbuf = (u16*)alloc(actB);
  u16* wqb = (u16*)alloc(wB);
  u16* wkb = (u16*)alloc(wB);
  u16* wvb = (u16*)alloc(wB);
  u16* wob = (u16*)alloc(wB);
  u16* Qh = (u16*)alloc(actB);
  u16* Kh = (u16*)alloc(actB);
  u16* Vt = (u16*)alloc(actB);
  u16* Xb = qbuf;   // reuse: query_bf16 dead after Q projection

  CastArgs ca;
  ca.src[0] = query; ca.src[1] = key_; ca.src[2] = value;
  ca.src[3] = Wq; ca.src[4] = Wk; ca.src[5] = Wv; ca.src[6] = Wo;
  ca.dst[0] = qbuf; ca.dst[1] = kbuf; ca.dst[2] = vbuf;
  ca.dst[3] = wqb; ca.dst[4] = wkb; ca.dst[5] = wvb; ca.dst[6] = wob;
  ca.n[0] = ca.n[1] = ca.n[2] = Mn * Dn;
  ca.n[3] = ca.n[4] = ca.n[5] = ca.n[6] = Dn * Dn;
  cast_kernel<<<dim3(1024, 7), 256, 0, stream>>>(ca);

  gemm_bt<0><<<dim3(512), 256, 0, stream>>>(qbuf, wqb, bq, Qh);
  gemm_bt<1><<<dim3(512), 256, 0, stream>>>(kbuf, wkb, bk, Kh);
  gemm_bt<2><<<dim3(512), 256, 0, stream>>>(vbuf, wvb, bv, Vt);
  flash_attn<<<dim3(Bn * Hn * (Sn / 128)), 256, 0, stream>>>(Qh, Kh, Vt, Xb);
  gemm_bt<3><<<dim3(512), 256, 0, stream>>>(Xb, wob, bo, (float*)d_out);
}

// Round 4
// 283.413 us; speedup vs baseline: 1.9128x; 1.3377x over previous
//
#include <hip/hip_runtime.h>
#include <stdint.h>

#define DEVI __device__ __forceinline__

typedef __attribute__((ext_vector_type(8))) __bf16 bf16x8;
typedef __attribute__((ext_vector_type(4))) __bf16 bf16x4;
typedef __attribute__((ext_vector_type(4))) float f32x4;
typedef __attribute__((ext_vector_type(4))) unsigned short u16x4;
typedef unsigned short u16;

constexpr int Bn = 4, Sn = 2048, Dn = 1024, Hn = 16;
constexpr int Mn = Bn * Sn;                               // 8192
constexpr float QSCALE = 1.4426950408889634f / 32.0f;     // log2(e)/sqrt(D): folds softmax scale + exp2 base

// ---------- helpers ----------
DEVI u16 f2bf(float f) {                                  // RNE f32 -> bf16 bits
  uint32_t u = __builtin_bit_cast(uint32_t, f);
  u += 0x7fffu + ((u >> 16) & 1u);
  return (u16)(u >> 16);
}

typedef __attribute__((address_space(1))) void gvoid;
typedef __attribute__((address_space(3))) void lvoid;
DEVI void gload_lds16(const void* g, void* l) {
  // LDS dest is wave-uniform base + lane*16 (pass base only)
  __builtin_amdgcn_global_load_lds((gvoid*)(uintptr_t)g,
                                   (lvoid*)(uint32_t)(uintptr_t)l, 16, 0, 0);
}

DEVI f32x4 mfma16(bf16x8 a, bf16x8 b, f32x4 c) {
  return __builtin_amdgcn_mfma_f32_16x16x32_bf16(a, b, c, 0, 0, 0);
}

// ---------- cast fp32 -> bf16 ----------
struct CastArgs {
  const float* src[7];
  u16* dst[7];
  int n[7];
};

__global__ __launch_bounds__(256) void cast_kernel(CastArgs a) {
  const int seg = blockIdx.y;
  const float* __restrict__ src = a.src[seg];
  u16* __restrict__ dst = a.dst[seg];
  const int n = a.n[seg];
  const int stride = gridDim.x * 256 * 4;
  for (int i = (blockIdx.x * 256 + threadIdx.x) * 4; i < n; i += stride) {
    const float4 v = *reinterpret_cast<const float4*>(src + i);
    u16x4 p;
    p[0] = f2bf(v.x); p[1] = f2bf(v.y); p[2] = f2bf(v.z); p[3] = f2bf(v.w);
    *reinterpret_cast<u16x4*>(dst + i) = p;
  }
}

// ---------- GEMM: C[m][n] = sum_k A[m][k]*Bt[n][k] + bias[n] ----------
// MODE 0: Q out, bf16 [B][H][S][64], scaled by QSCALE
// MODE 1: K out, bf16 [B][H][S][64]
// MODE 2: V out, bf16 [B][H][64][S]  (transposed for PV B-fragments)
// MODE 3: fp32 out [M][N]
template <int MODE>
__global__ __launch_bounds__(256)
void gemm_bt(const u16* __restrict__ A, const u16* __restrict__ Bt,
             const float* __restrict__ bias, void* __restrict__ out) {
  constexpr int BK = 32, Kd = 1024;
  __shared__ __align__(16) u16 As[128 * BK];   // 8 KB
  __shared__ __align__(16) u16 Bs[128 * BK];   // 8 KB

  const int tid = threadIdx.x;
  const int lane = tid & 63;
  const int w = tid >> 6;             // 4 waves, 2x2
  const int wr = w >> 1, wc = w & 1;
  const int mt = blockIdx.x >> 3, nt = blockIdx.x & 7;   // 64 x 8 tiles
  const int m0 = mt * 128, n0 = nt * 128;
  const int c = lane & 15, g = lane >> 4;

  f32x4 acc[4][4] = {};

  // staging: chunk = (i*4+w)*64 + lane -> row = chunk>>2, col8 = (chunk&3)*8
  const u16* aA[2];
  const u16* aB[2];
  int loff[2];
  #pragma unroll
  for (int i = 0; i < 2; ++i) {
    const int chunk = (i * 4 + w) * 64 + lane;
    const int row = chunk >> 2, col = (chunk & 3) * 8;
    aA[i] = A + (size_t)(m0 + row) * Kd + col;
    aB[i] = Bt + (size_t)(n0 + row) * Kd + col;
    loff[i] = (i * 4 + w) * 1024;     // bytes
  }

  for (int kt = 0; kt < Kd; kt += BK) {
    #pragma unroll
    for (int i = 0; i < 2; ++i) {
      gload_lds16(aA[i] + kt, (char*)As + loff[i]);
      gload_lds16(aB[i] + kt, (char*)Bs + loff[i]);
    }
    __syncthreads();                  // drains vmcnt before barrier
    bf16x8 af[4], bfr[4];
    #pragma unroll
    for (int i = 0; i < 4; ++i) {
      af[i]  = *(const bf16x8*)(As + (wr * 64 + i * 16 + c) * BK + g * 8);
      bfr[i] = *(const bf16x8*)(Bs + (wc * 64 + i * 16 + c) * BK + g * 8);
    }
    #pragma unroll
    for (int mi = 0; mi < 4; ++mi)
      #pragma unroll
      for (int ni = 0; ni < 4; ++ni)
        acc[mi][ni] = mfma16(af[mi], bfr[ni], acc[mi][ni]);
    __syncthreads();                  // all reads done before next stage
  }

  // epilogue; C/D layout: col = lane&15, row = (lane>>4)*4 + reg
  #pragma unroll
  for (int mi = 0; mi < 4; ++mi) {
    #pragma unroll
    for (int ni = 0; ni < 4; ++ni) {
      const int n = n0 + wc * 64 + ni * 16 + c;
      const float bv = bias[n];
      const int mb = m0 + wr * 64 + mi * 16 + g * 4;
      const f32x4 v = acc[mi][ni];
      if constexpr (MODE == 0 || MODE == 1) {
        u16* dst = (u16*)out;
        const int h = n >> 6, hd = n & 63;
        #pragma unroll
        for (int j = 0; j < 4; ++j) {
          const int m = mb + j;
          const int b = m >> 11, s = m & 2047;
          float val = v[j] + bv;
          if constexpr (MODE == 0) val *= QSCALE;
          dst[(((size_t)(b * Hn + h) * Sn + s) << 6) + hd] = f2bf(val);
        }
      } else if constexpr (MODE == 2) {
        u16* dst = (u16*)out;
        const int h = n >> 6, hd = n & 63;
        const int b = mb >> 11, s = mb & 2047;   // 4 consecutive s, same b
        u16x4 pk;
        #pragma unroll
        for (int j = 0; j < 4; ++j) pk[j] = f2bf(v[j] + bv);
        *(u16x4*)(dst + ((size_t)((b * Hn + h) * 64 + hd)) * Sn + s) = pk;
      } else {
        float* dst = (float*)out;
        #pragma unroll
        for (int j = 0; j < 4; ++j)
          dst[(size_t)(mb + j) * Dn + n] = v[j] + bv;
      }
    }
  }
}

// ---------- flash attention (LDS-staged K/V, 2-phase pipeline) ----------
// Q [B*H][S][64] (prescaled by QSCALE), K [B*H][S][64], Vt [B*H][64][S]
// X out bf16 [B][S][D]. Grid: 1024 blocks; bid = qt*64 + bh so the 16 q-tile
// blocks of one (b,h) share an XCD L2. 4 waves/block, 32 q-rows/wave; all
// waves consume the SAME K/V tile, staged cooperatively into double-buffered
// LDS via global_load_lds. Stage(t+1) is in flight across the whole compute
// of tile t; one __syncthreads() (vmcnt0+barrier) per tile.
// K/V LDS tiles are 64 rows x 128B: raw ds_read_b128 would be 16-way bank
// conflicted, so storage is XOR-swizzled (byte ^= (row&7)<<4) by pre-swizzling
// the global source address (linear LDS dest) and xoring the read address.
__global__ __launch_bounds__(256)
void flash_attn(const u16* __restrict__ Q, const u16* __restrict__ K,
                const u16* __restrict__ Vt, u16* __restrict__ X) {
  __shared__ __align__(16) u16 Ks[2][4096];      // 16 KB double-buffered K tile
  __shared__ __align__(16) u16 Vs[2][4096];      // 16 KB double-buffered V tile
  __shared__ __align__(16) u16 Plds[4][2][512];  // 8 KB per-wave P scratch

  const int tid = threadIdx.x, lane = tid & 63, w = tid >> 6;
  const int bid = blockIdx.x;
  const int bh = bid & 63, qt = bid >> 6;
  const int b = bh >> 4, h = bh & 15;
  const int q0 = qt * 128 + w * 32;
  const int c = lane & 15, g = lane >> 4;

  const u16* Qb = Q + (size_t)bh * Sn * 64;
  const u16* Kb = K + (size_t)bh * Sn * 64;
  const u16* Vb = Vt + (size_t)bh * 64 * Sn;

  // staging geometry: thread covers 16B chunks (i*4+w)*64+lane, i=0,1.
  // chunk -> (row = chunk>>3, colb = (chunk&7)*16); source col pre-swizzled.
  int srcK[2], srcV[2], ldsOff[2];
  #pragma unroll
  for (int i = 0; i < 2; ++i) {
    const int chunk = (i * 4 + w) * 64 + lane;
    const int row = chunk >> 3;
    const int colb = (chunk & 7) * 16;
    const int scol = (colb ^ ((row & 7) << 4)) >> 1;   // elements
    srcK[i] = row * 64 + scol;        // + kv*64 per tile
    srcV[i] = row * Sn + scol;        // + kv per tile
    ldsOff[i] = (i * 4 + w) * 1024;   // bytes; HW adds lane*16
  }
  auto stage = [&](int buf, int kv_) {
    #pragma unroll
    for (int i = 0; i < 2; ++i) {
      gload_lds16(Kb + (size_t)kv_ * 64 + srcK[i], (char*)Ks[buf] + ldsOff[i]);
      gload_lds16(Vb + kv_ + srcV[i], (char*)Vs[buf] + ldsOff[i]);
    }
  };

  // Q as B-operand fragments: lane (c,g) holds Q[q0+qi*16+c][ks*32+g*8 ..+7]
  bf16x8 qf[2][2];
  #pragma unroll
  for (int qi = 0; qi < 2; ++qi)
    #pragma unroll
    for (int ks = 0; ks < 2; ++ks)
      qf[qi][ks] = *(const bf16x8*)(Qb + (size_t)(q0 + qi * 16 + c) * 64 + ks * 32 + g * 8);

  stage(0, 0);

  f32x4 o[2][4] = {};
  float m2[2] = {-1.0e30f, -1.0e30f};   // running max for q = q0 + qi*16 + c
  float l2[2] = {0.f, 0.f};

  __syncthreads();   // stage(0) complete

  int cur = 0;
  for (int kv = 0; kv < Sn; kv += 64) {
    const int kvn = (kv + 64) & (Sn - 1);   // last-iter wraps (unused, in-bounds)
    stage(cur ^ 1, kvn);                    // in flight during whole tile compute

    // ---- QK^T from Ks[cur]: sc[qi][kf] has col=q=(qi*16+c), row=k=(kf*16+g*4+j)
    f32x4 sc[2][4] = {};
    #pragma unroll
    for (int ks = 0; ks < 2; ++ks) {
      bf16x8 kfr[4];
      #pragma unroll
      for (int kf = 0; kf < 4; ++kf) {
        const int r = kf * 16 + c;
        const int cb = (ks * 64 + g * 16) ^ ((r & 7) << 4);
        kfr[kf] = *(const bf16x8*)((const char*)Ks[cur] + r * 128 + cb);
      }
      __builtin_amdgcn_s_setprio(1);
      #pragma unroll
      for (int kf = 0; kf < 4; ++kf) {
        sc[0][kf] = mfma16(kfr[kf], qf[0][ks], sc[0][kf]);
        sc[1][kf] = mfma16(kfr[kf], qf[1][ks], sc[1][kf]);
      }
      __builtin_amdgcn_s_setprio(0);
    }

    // ---- per-q max: 16 in-lane values, then reduce across the 4 g-groups
    float mx[2];
    #pragma unroll
    for (int qi = 0; qi < 2; ++qi) {
      float t0 = fmaxf(fmaxf(sc[qi][0][0], sc[qi][0][1]), fmaxf(sc[qi][0][2], sc[qi][0][3]));
      float t1 = fmaxf(fmaxf(sc[qi][1][0], sc[qi][1][1]), fmaxf(sc[qi][1][2], sc[qi][1][3]));
      float t2 = fmaxf(fmaxf(sc[qi][2][0], sc[qi][2][1]), fmaxf(sc[qi][2][2], sc[qi][2][3]));
      float t3 = fmaxf(fmaxf(sc[qi][3][0], sc[qi][3][1]), fmaxf(sc[qi][3][2], sc[qi][3][3]));
      float t = fmaxf(fmaxf(t0, t1), fmaxf(t2, t3));
      t = fmaxf(t, __shfl_xor(t, 16));
      t = fmaxf(t, __shfl_xor(t, 32));
      mx[qi] = t;
    }

    // ---- T13 defer-max: skip O-rescale when max growth small (P <= 2^8)
    const float growth = fmaxf(mx[0] - m2[0], mx[1] - m2[1]);
    if (!__all(growth <= 8.0f)) {
      float alpha[2];
      #pragma unroll
      for (int qi = 0; qi < 2; ++qi) {
        const float mnew = fmaxf(m2[qi], mx[qi]);
        alpha[qi] = __builtin_exp2f(m2[qi] - mnew);
        m2[qi] = mnew;
        l2[qi] *= alpha[qi];
      }
      #pragma unroll
      for (int qi = 0; qi < 2; ++qi) {
        #pragma unroll
        for (int j = 0; j < 4; ++j) {
          const float aj = __shfl(alpha[qi], 4 * g + j);
          #pragma unroll
          for (int nd = 0; nd < 4; ++nd) o[qi][nd][j] *= aj;
        }
      }
    }

    // ---- P = exp2(S - m): pack to bf16, per-wave LDS transpose to A-frag
    // order (sequential qi, buffer reused; per-wave DS pipe is in-order).
    // Value at lane(c,g) reg j of frag(qi,kf) is P[q=qi*16+c][k=kf*16+g*4+j];
    // dest frag ks2=kf>>1, lane-slot ((kf&1)*2+(g>>1))*16+c, elem off (g&1)*4.
    bf16x8 pa[2][2];
    #pragma unroll
    for (int qi = 0; qi < 2; ++qi) {
      float s = 0.f;
      #pragma unroll
      for (int kf = 0; kf < 4; ++kf) {
        bf16x4 pk;
        #pragma unroll
        for (int j = 0; j < 4; ++j) {
          const float p = __builtin_exp2f(sc[qi][kf][j] - m2[qi]);
          s += p;
          pk[j] = (__bf16)p;
        }
        const int gp = (kf & 1) * 2 + (g >> 1);
        *(bf16x4*)&Plds[w][kf >> 1][(gp * 16 + c) * 8 + (g & 1) * 4] = pk;
      }
      pa[qi][0] = *(const bf16x8*)&Plds[w][0][lane * 8];
      pa[qi][1] = *(const bf16x8*)&Plds[w][1][lane * 8];
      s += __shfl_xor(s, 16);
      s += __shfl_xor(s, 32);
      l2[qi] += s;
    }

    // ---- PV: O[32][64] += P[32][64] * V[64][64], V frags from Vs[cur]
    #pragma unroll
    for (int ks2 = 0; ks2 < 2; ++ks2) {
      bf16x8 vfr[4];
      #pragma unroll
      for (int nd = 0; nd < 4; ++nd) {
        const int r = nd * 16 + c;
        const int cb = (ks2 * 64 + g * 16) ^ ((r & 7) << 4);
        vfr[nd] = *(const bf16x8*)((const char*)Vs[cur] + r * 128 + cb);
      }
      __builtin_amdgcn_s_setprio(1);
      #pragma unroll
      for (int nd = 0; nd < 4; ++nd) {
        o[0][nd] = mfma16(pa[0][ks2], vfr[nd], o[0][nd]);
        o[1][nd] = mfma16(pa[1][ks2], vfr[nd], o[1][nd]);
      }
      __builtin_amdgcn_s_setprio(0);
    }

    __syncthreads();   // stage(t+1) landed (vmcnt0) + all reads of buf[cur] done
    cur ^= 1;
  }

  // epilogue: transpose 1/l to O layout, normalize, store
  #pragma unroll
  for (int qi = 0; qi < 2; ++qi) {
    const float rl = 1.0f / l2[qi];
    #pragma unroll
    for (int j = 0; j < 4; ++j) {
      const float rn = __shfl(rl, 4 * g + j);
      const int s = q0 + qi * 16 + g * 4 + j;
      u16* dst = X + (size_t)(b * Sn + s) * Dn + h * 64 + c;
      #pragma unroll
      for (int nd = 0; nd < 4; ++nd)
        dst[nd * 16] = f2bf(o[qi][nd][j] * rn);
    }
  }
}

// ---------- launch ----------
extern "C" void kernel_launch(void* const* d_in, const int* in_sizes, int n_in,
                              void* d_out, int out_size, void* d_ws, size_t ws_size,
                              hipStream_t stream) {
  (void)in_sizes; (void)n_in; (void)out_size; (void)ws_size;
  const float* query = (const float*)d_in[0];
  const float* key_  = (const float*)d_in[1];
  const float* value = (const float*)d_in[2];
  const float* Wq = (const float*)d_in[3];
  const float* bq = (const float*)d_in[4];
  const float* Wk = (const float*)d_in[5];
  const float* bk = (const float*)d_in[6];
  const float* Wv = (const float*)d_in[7];
  const float* bv = (const float*)d_in[8];
  const float* Wo = (const float*)d_in[9];
  const float* bo = (const float*)d_in[10];

  char* ws = (char*)d_ws;
  size_t off = 0;
  auto alloc = [&](size_t bytes) {
    void* p = ws + off;
    off += (bytes + 255) & ~(size_t)255;
    return p;
  };
  const size_t actB = (size_t)Mn * Dn * 2;   // 16 MB
  const size_t wB = (size_t)Dn * Dn * 2;     // 2 MB
  u16* qbuf = (u16*)alloc(actB);
  u16* kbuf = (u16*)alloc(actB);
  u16* vbuf = (u16*)alloc(actB);
  u16* wqb = (u16*)alloc(wB);
  u16* wkb = (u16*)alloc(wB);
  u16* wvb = (u16*)alloc(wB);
  u16* wob = (u16*)alloc(wB);
  u16* Qh = (u16*)alloc(actB);
  u16* Kh = (u16*)alloc(actB);
  u16* Vt = (u16*)alloc(actB);
  u16* Xb = qbuf;   // reuse: query_bf16 dead after Q projection

  CastArgs ca;
  ca.src[0] = query; ca.src[1] = key_; ca.src[2] = value;
  ca.src[3] = Wq; ca.src[4] = Wk; ca.src[5] = Wv; ca.src[6] = Wo;
  ca.dst[0] = qbuf; ca.dst[1] = kbuf; ca.dst[2] = vbuf;
  ca.dst[3] = wqb; ca.dst[4] = wkb; ca.dst[5] = wvb; ca.dst[6] = wob;
  ca.n[0] = ca.n[1] = ca.n[2] = Mn * Dn;
  ca.n[3] = ca.n[4] = ca.n[5] = ca.n[6] = Dn * Dn;
  cast_kernel<<<dim3(1024, 7), 256, 0, stream>>>(ca);

  gemm_bt<0><<<dim3(512), 256, 0, stream>>>(qbuf, wqb, bq, Qh);
  gemm_bt<1><<<dim3(512), 256, 0, stream>>>(kbuf, wkb, bk, Kh);
  gemm_bt<2><<<dim3(512), 256, 0, stream>>>(vbuf, wvb, bv, Vt);
  flash_attn<<<dim3(Bn * Hn * (Sn / 128)), 256, 0, stream>>>(Qh, Kh, Vt, Xb);
  gemm_bt<3><<<dim3(512), 256, 0, stream>>>(Xb, wob, bo, (float*)d_out);
}

// Round 5
// 278.242 us; speedup vs baseline: 1.9483x; 1.0186x over previous
//
#include <hip/hip_runtime.h>
#include <stdint.h>

#define DEVI __device__ __forceinline__

typedef __attribute__((ext_vector_type(8))) __bf16 bf16x8;
typedef __attribute__((ext_vector_type(4))) __bf16 bf16x4;
typedef __attribute__((ext_vector_type(4))) float f32x4;
typedef __attribute__((ext_vector_type(4))) unsigned short u16x4;
typedef __attribute__((ext_vector_type(4))) unsigned int u32x4;
typedef unsigned short u16;

constexpr int Bn = 4, Sn = 2048, Dn = 1024, Hn = 16;
constexpr int Mn = Bn * Sn;                               // 8192
constexpr float QSCALE = 1.4426950408889634f / 32.0f;     // log2(e)/sqrt(D): folds softmax scale + exp2 base

// ---------- helpers ----------
DEVI u16 f2bf(float f) {                                  // RNE f32 -> bf16 bits
  uint32_t u = __builtin_bit_cast(uint32_t, f);
  u += 0x7fffu + ((u >> 16) & 1u);
  return (u16)(u >> 16);
}

typedef __attribute__((address_space(1))) void gvoid;
typedef __attribute__((address_space(3))) void lvoid;
DEVI void gload_lds16(const void* g, void* l) {
  // LDS dest is wave-uniform base + lane*16 (pass base only)
  __builtin_amdgcn_global_load_lds((gvoid*)(uintptr_t)g,
                                   (lvoid*)(uint32_t)(uintptr_t)l, 16, 0, 0);
}

DEVI f32x4 mfma16(bf16x8 a, bf16x8 b, f32x4 c) {
  return __builtin_amdgcn_mfma_f32_16x16x32_bf16(a, b, c, 0, 0, 0);
}

// ---------- cast fp32 -> bf16 ----------
struct CastArgs {
  const float* src[7];
  u16* dst[7];
  int n[7];
};

__global__ __launch_bounds__(256) void cast_kernel(CastArgs a) {
  const int seg = blockIdx.y;
  const float* __restrict__ src = a.src[seg];
  u16* __restrict__ dst = a.dst[seg];
  const int n = a.n[seg];
  const int stride = gridDim.x * 256 * 4;
  for (int i = (blockIdx.x * 256 + threadIdx.x) * 4; i < n; i += stride) {
    const float4 v = *reinterpret_cast<const float4*>(src + i);
    u16x4 p;
    p[0] = f2bf(v.x); p[1] = f2bf(v.y); p[2] = f2bf(v.z); p[3] = f2bf(v.w);
    *reinterpret_cast<u16x4*>(dst + i) = p;
  }
}

// ---------- GEMM: C[m][n] = sum_k A[m][k]*Bt[n][k] + bias[n] ----------
// MODE 0: Q out, bf16 [B][H][S][64], scaled by QSCALE
// MODE 1: K out, bf16 [B][H][S][64]
// MODE 2: V out, bf16 [B][H][64][S]  (transposed for PV B-fragments)
// MODE 3: fp32 out [M][N]
template <int MODE>
__global__ __launch_bounds__(256)
void gemm_bt(const u16* __restrict__ A, const u16* __restrict__ Bt,
             const float* __restrict__ bias, void* __restrict__ out) {
  constexpr int BK = 32, Kd = 1024;
  __shared__ __align__(16) u16 As[128 * BK];   // 8 KB
  __shared__ __align__(16) u16 Bs[128 * BK];   // 8 KB

  const int tid = threadIdx.x;
  const int lane = tid & 63;
  const int w = tid >> 6;             // 4 waves, 2x2
  const int wr = w >> 1, wc = w & 1;
  const int mt = blockIdx.x >> 3, nt = blockIdx.x & 7;   // 64 x 8 tiles
  const int m0 = mt * 128, n0 = nt * 128;
  const int c = lane & 15, g = lane >> 4;

  f32x4 acc[4][4] = {};

  // staging: chunk = (i*4+w)*64 + lane -> row = chunk>>2, col8 = (chunk&3)*8
  const u16* aA[2];
  const u16* aB[2];
  int loff[2];
  #pragma unroll
  for (int i = 0; i < 2; ++i) {
    const int chunk = (i * 4 + w) * 64 + lane;
    const int row = chunk >> 2, col = (chunk & 3) * 8;
    aA[i] = A + (size_t)(m0 + row) * Kd + col;
    aB[i] = Bt + (size_t)(n0 + row) * Kd + col;
    loff[i] = (i * 4 + w) * 1024;     // bytes
  }

  for (int kt = 0; kt < Kd; kt += BK) {
    #pragma unroll
    for (int i = 0; i < 2; ++i) {
      gload_lds16(aA[i] + kt, (char*)As + loff[i]);
      gload_lds16(aB[i] + kt, (char*)Bs + loff[i]);
    }
    __syncthreads();                  // drains vmcnt before barrier
    bf16x8 af[4], bfr[4];
    #pragma unroll
    for (int i = 0; i < 4; ++i) {
      af[i]  = *(const bf16x8*)(As + (wr * 64 + i * 16 + c) * BK + g * 8);
      bfr[i] = *(const bf16x8*)(Bs + (wc * 64 + i * 16 + c) * BK + g * 8);
    }
    #pragma unroll
    for (int mi = 0; mi < 4; ++mi)
      #pragma unroll
      for (int ni = 0; ni < 4; ++ni)
        acc[mi][ni] = mfma16(af[mi], bfr[ni], acc[mi][ni]);
    __syncthreads();                  // all reads done before next stage
  }

  // epilogue; C/D layout: col = lane&15, row = (lane>>4)*4 + reg
  #pragma unroll
  for (int mi = 0; mi < 4; ++mi) {
    #pragma unroll
    for (int ni = 0; ni < 4; ++ni) {
      const int n = n0 + wc * 64 + ni * 16 + c;
      const float bv = bias[n];
      const int mb = m0 + wr * 64 + mi * 16 + g * 4;
      const f32x4 v = acc[mi][ni];
      if constexpr (MODE == 0 || MODE == 1) {
        u16* dst = (u16*)out;
        const int h = n >> 6, hd = n & 63;
        #pragma unroll
        for (int j = 0; j < 4; ++j) {
          const int m = mb + j;
          const int b = m >> 11, s = m & 2047;
          float val = v[j] + bv;
          if constexpr (MODE == 0) val *= QSCALE;
          dst[(((size_t)(b * Hn + h) * Sn + s) << 6) + hd] = f2bf(val);
        }
      } else if constexpr (MODE == 2) {
        u16* dst = (u16*)out;
        const int h = n >> 6, hd = n & 63;
        const int b = mb >> 11, s = mb & 2047;   // 4 consecutive s, same b
        u16x4 pk;
        #pragma unroll
        for (int j = 0; j < 4; ++j) pk[j] = f2bf(v[j] + bv);
        *(u16x4*)(dst + ((size_t)((b * Hn + h) * 64 + hd)) * Sn + s) = pk;
      } else {
        float* dst = (float*)out;
        #pragma unroll
        for (int j = 0; j < 4; ++j)
          dst[(size_t)(mb + j) * Dn + n] = v[j] + bv;
      }
    }
  }
}

// ---------- flash attention (LDS K/V dbuf + in-register P via permlane) ----------
// Q [B*H][S][64] (prescaled by QSCALE), K [B*H][S][64], Vt [B*H][64][S]
// X out bf16 [B][S][D]. Grid: 1024 blocks; bid = qt*64 + bh (XCD locality).
// 4 waves/block, 32 q-rows/wave. K/V staged to double-buffered LDS via
// global_load_lds (XOR-swizzled: pre-swizzled source + swizzled read).
// P transpose to PV-A-fragment layout is done IN REGISTER (T12):
//   cvt_pk_bf16 pairs -> 2x permlane32_swap + 2x permlane16_swap per (qi,ks2).
// Row-sum l computed by MFMA against a ones-B fragment (lands in O-row
// layout: no shuffles, epilogue divides directly).
__global__ __launch_bounds__(256, 4)
void flash_attn(const u16* __restrict__ Q, const u16* __restrict__ K,
                const u16* __restrict__ Vt, u16* __restrict__ X) {
  __shared__ __align__(16) u16 Ks[2][4096];      // 16 KB double-buffered K tile
  __shared__ __align__(16) u16 Vs[2][4096];      // 16 KB double-buffered V tile

  const int tid = threadIdx.x, lane = tid & 63, w = tid >> 6;
  const int bid = blockIdx.x;
  const int bh = bid & 63, qt = bid >> 6;
  const int b = bh >> 4, h = bh & 15;
  const int q0 = qt * 128 + w * 32;
  const int c = lane & 15, g = lane >> 4;

  const u16* Qb = Q + (size_t)bh * Sn * 64;
  const u16* Kb = K + (size_t)bh * Sn * 64;
  const u16* Vb = Vt + (size_t)bh * 64 * Sn;

  // staging geometry: thread covers 16B chunks (i*4+w)*64+lane, i=0,1.
  // chunk -> (row = chunk>>3, colb = (chunk&7)*16); source col pre-swizzled.
  int srcK[2], srcV[2], ldsOff[2];
  #pragma unroll
  for (int i = 0; i < 2; ++i) {
    const int chunk = (i * 4 + w) * 64 + lane;
    const int row = chunk >> 3;
    const int colb = (chunk & 7) * 16;
    const int scol = (colb ^ ((row & 7) << 4)) >> 1;   // elements
    srcK[i] = row * 64 + scol;        // + kv*64 per tile
    srcV[i] = row * Sn + scol;        // + kv per tile
    ldsOff[i] = (i * 4 + w) * 1024;   // bytes; HW adds lane*16
  }
  auto stage = [&](int buf, int kv_) {
    #pragma unroll
    for (int i = 0; i < 2; ++i) {
      gload_lds16(Kb + (size_t)kv_ * 64 + srcK[i], (char*)Ks[buf] + ldsOff[i]);
      gload_lds16(Vb + kv_ + srcV[i], (char*)Vs[buf] + ldsOff[i]);
    }
  };

  // Q as B-operand fragments: lane (c,g) holds Q[q0+qi*16+c][ks*32+g*8 ..+7]
  bf16x8 qf[2][2];
  #pragma unroll
  for (int qi = 0; qi < 2; ++qi)
    #pragma unroll
    for (int ks = 0; ks < 2; ++ks)
      qf[qi][ks] = *(const bf16x8*)(Qb + (size_t)(q0 + qi * 16 + c) * 64 + ks * 32 + g * 8);

  bf16x8 ONES;
  #pragma unroll
  for (int e = 0; e < 8; ++e) ONES[e] = (__bf16)1.0f;

  stage(0, 0);

  f32x4 o[2][4] = {};
  f32x4 lacc[2] = {};                   // row-sum l in O layout: q = qi*16+g*4+j
  float m2[2] = {-1.0e30f, -1.0e30f};   // running max in c layout: q = qi*16+c

  __syncthreads();   // stage(0) complete

  int cur = 0;
  for (int kv = 0; kv < Sn; kv += 64) {
    const int kvn = (kv + 64) & (Sn - 1);   // last-iter wraps (unused, in-bounds)
    stage(cur ^ 1, kvn);                    // in flight during whole tile compute

    // ---- QK^T from Ks[cur]: sc[qi][kf] has col=q=(qi*16+c), row=k=(kf*16+g*4+j)
    f32x4 sc[2][4] = {};
    #pragma unroll
    for (int ks = 0; ks < 2; ++ks) {
      bf16x8 kfr[4];
      #pragma unroll
      for (int kf = 0; kf < 4; ++kf) {
        const int r = kf * 16 + c;
        const int cb = (ks * 64 + g * 16) ^ ((r & 7) << 4);
        kfr[kf] = *(const bf16x8*)((const char*)Ks[cur] + r * 128 + cb);
      }
      __builtin_amdgcn_s_setprio(1);
      #pragma unroll
      for (int kf = 0; kf < 4; ++kf) {
        sc[0][kf] = mfma16(kfr[kf], qf[0][ks], sc[0][kf]);
        sc[1][kf] = mfma16(kfr[kf], qf[1][ks], sc[1][kf]);
      }
      __builtin_amdgcn_s_setprio(0);
    }

    // ---- per-q max: 16 in-lane values, then reduce across the 4 g-groups
    float mx[2];
    #pragma unroll
    for (int qi = 0; qi < 2; ++qi) {
      float t0 = fmaxf(fmaxf(sc[qi][0][0], sc[qi][0][1]), fmaxf(sc[qi][0][2], sc[qi][0][3]));
      float t1 = fmaxf(fmaxf(sc[qi][1][0], sc[qi][1][1]), fmaxf(sc[qi][1][2], sc[qi][1][3]));
      float t2 = fmaxf(fmaxf(sc[qi][2][0], sc[qi][2][1]), fmaxf(sc[qi][2][2], sc[qi][2][3]));
      float t3 = fmaxf(fmaxf(sc[qi][3][0], sc[qi][3][1]), fmaxf(sc[qi][3][2], sc[qi][3][3]));
      float t = fmaxf(fmaxf(t0, t1), fmaxf(t2, t3));
      t = fmaxf(t, __shfl_xor(t, 16));
      t = fmaxf(t, __shfl_xor(t, 32));
      mx[qi] = t;
    }

    // ---- T13 defer-max: skip O/l-rescale when max growth small (P <= 2^8)
    const float growth = fmaxf(mx[0] - m2[0], mx[1] - m2[1]);
    if (!__all(growth <= 8.0f)) {
      float alpha[2];
      #pragma unroll
      for (int qi = 0; qi < 2; ++qi) {
        const float mnew = fmaxf(m2[qi], mx[qi]);
        alpha[qi] = __builtin_exp2f(m2[qi] - mnew);
        m2[qi] = mnew;
      }
      #pragma unroll
      for (int qi = 0; qi < 2; ++qi) {
        #pragma unroll
        for (int j = 0; j < 4; ++j) {
          const float aj = __shfl(alpha[qi], 4 * g + j);
          #pragma unroll
          for (int nd = 0; nd < 4; ++nd) o[qi][nd][j] *= aj;
          lacc[qi][j] *= aj;
        }
      }
    }

    // ---- P = exp2(S - m) -> bf16 pairs -> in-register transpose to A-frags.
    // Source word wv[kf][t'] at lane(c,g) = P[q=qi*16+c][k=kf*16+g*4+2t'+{0,1}]
    // Target pa[ks2] word u[t] at lane(c,g') = P[q][k=ks2*32+g'*8+2t+{0,1}]
    // Routing (verified): A=wv[2k][0],B=wv[2k][1],C=wv[2k+1][0],D=wv[2k+1][1];
    //   permlane32_swap(A,C); permlane32_swap(B,D);
    //   permlane16_swap(A,C); permlane16_swap(B,D);  -> u0=A,u1=B,u2=C,u3=D
    bf16x8 pa[2][2];
    #pragma unroll
    for (int qi = 0; qi < 2; ++qi) {
      uint32_t wv[4][2];
      #pragma unroll
      for (int kf = 0; kf < 4; ++kf) {
        const float p0 = __builtin_exp2f(sc[qi][kf][0] - m2[qi]);
        const float p1 = __builtin_exp2f(sc[qi][kf][1] - m2[qi]);
        const float p2 = __builtin_exp2f(sc[qi][kf][2] - m2[qi]);
        const float p3 = __builtin_exp2f(sc[qi][kf][3] - m2[qi]);
        asm("v_cvt_pk_bf16_f32 %0, %1, %2" : "=v"(wv[kf][0]) : "v"(p0), "v"(p1));
        asm("v_cvt_pk_bf16_f32 %0, %1, %2" : "=v"(wv[kf][1]) : "v"(p2), "v"(p3));
      }
      #pragma unroll
      for (int ks2 = 0; ks2 < 2; ++ks2) {
        uint32_t ua = wv[2 * ks2][0], ub = wv[2 * ks2][1];
        uint32_t uc = wv[2 * ks2 + 1][0], ud = wv[2 * ks2 + 1][1];
        asm("v_permlane32_swap_b32 %0, %1" : "+v"(ua), "+v"(uc));
        asm("v_permlane32_swap_b32 %0, %1" : "+v"(ub), "+v"(ud));
        asm("v_permlane16_swap_b32 %0, %1" : "+v"(ua), "+v"(uc));
        asm("v_permlane16_swap_b32 %0, %1" : "+v"(ub), "+v"(ud));
        const u32x4 uv = {ua, ub, uc, ud};
        pa[qi][ks2] = __builtin_bit_cast(bf16x8, uv);
      }
    }

    // ---- l += P . 1 via MFMA (lands in O layout: row q = g*4+j, col-uniform)
    lacc[0] = mfma16(pa[0][0], ONES, lacc[0]);
    lacc[0] = mfma16(pa[0][1], ONES, lacc[0]);
    lacc[1] = mfma16(pa[1][0], ONES, lacc[1]);
    lacc[1] = mfma16(pa[1][1], ONES, lacc[1]);

    // ---- PV: O[32][64] += P[32][64] * V[64][64], V frags from Vs[cur]
    #pragma unroll
    for (int ks2 = 0; ks2 < 2; ++ks2) {
      bf16x8 vfr[4];
      #pragma unroll
      for (int nd = 0; nd < 4; ++nd) {
        const int r = nd * 16 + c;
        const int cb = (ks2 * 64 + g * 16) ^ ((r & 7) << 4);
        vfr[nd] = *(const bf16x8*)((const char*)Vs[cur] + r * 128 + cb);
      }
      __builtin_amdgcn_s_setprio(1);
      #pragma unroll
      for (int nd = 0; nd < 4; ++nd) {
        o[0][nd] = mfma16(pa[0][ks2], vfr[nd], o[0][nd]);
        o[1][nd] = mfma16(pa[1][ks2], vfr[nd], o[1][nd]);
      }
      __builtin_amdgcn_s_setprio(0);
    }

    __syncthreads();   // stage(t+1) landed (vmcnt0) + all reads of buf[cur] done
    cur ^= 1;
  }

  // epilogue: l already in O layout; normalize and store
  #pragma unroll
  for (int qi = 0; qi < 2; ++qi) {
    #pragma unroll
    for (int j = 0; j < 4; ++j) {
      const float rn = 1.0f / lacc[qi][j];
      const int s = q0 + qi * 16 + g * 4 + j;
      u16* dst = X + (size_t)(b * Sn + s) * Dn + h * 64 + c;
      #pragma unroll
      for (int nd = 0; nd < 4; ++nd)
        dst[nd * 16] = f2bf(o[qi][nd][j] * rn);
    }
  }
}

// ---------- launch ----------
extern "C" void kernel_launch(void* const* d_in, const int* in_sizes, int n_in,
                              void* d_out, int out_size, void* d_ws, size_t ws_size,
                              hipStream_t stream) {
  (void)in_sizes; (void)n_in; (void)out_size; (void)ws_size;
  const float* query = (const float*)d_in[0];
  const float* key_  = (const float*)d_in[1];
  const float* value = (const float*)d_in[2];
  const float* Wq = (const float*)d_in[3];
  const float* bq = (const float*)d_in[4];
  const float* Wk = (const float*)d_in[5];
  const float* bk = (const float*)d_in[6];
  const float* Wv = (const float*)d_in[7];
  const float* bv = (const float*)d_in[8];
  const float* Wo = (const float*)d_in[9];
  const float* bo = (const float*)d_in[10];

  char* ws = (char*)d_ws;
  size_t off = 0;
  auto alloc = [&](size_t bytes) {
    void* p = ws + off;
    off += (bytes + 255) & ~(size_t)255;
    return p;
  };
  const size_t actB = (size_t)Mn * Dn * 2;   // 16 MB
  const size_t wB = (size_t)Dn * Dn * 2;     // 2 MB
  u16* qbuf = (u16*)alloc(actB);
  u16* kbuf = (u16*)alloc(actB);
  u16* vbuf = (u16*)alloc(actB);
  u16* wqb = (u16*)alloc(wB);
  u16* wkb = (u16*)alloc(wB);
  u16* wvb = (u16*)alloc(wB);
  u16* wob = (u16*)alloc(wB);
  u16* Qh = (u16*)alloc(actB);
  u16* Kh = (u16*)alloc(actB);
  u16* Vt = (u16*)alloc(actB);
  u16* Xb = qbuf;   // reuse: query_bf16 dead after Q projection

  CastArgs ca;
  ca.src[0] = query; ca.src[1] = key_; ca.src[2] = value;
  ca.src[3] = Wq; ca.src[4] = Wk; ca.src[5] = Wv; ca.src[6] = Wo;
  ca.dst[0] = qbuf; ca.dst[1] = kbuf; ca.dst[2] = vbuf;
  ca.dst[3] = wqb; ca.dst[4] = wkb; ca.dst[5] = wvb; ca.dst[6] = wob;
  ca.n[0] = ca.n[1] = ca.n[2] = Mn * Dn;
  ca.n[3] = ca.n[4] = ca.n[5] = ca.n[6] = Dn * Dn;
  cast_kernel<<<dim3(1024, 7), 256, 0, stream>>>(ca);

  gemm_bt<0><<<dim3(512), 256, 0, stream>>>(qbuf, wqb, bq, Qh);
  gemm_bt<1><<<dim3(512), 256, 0, stream>>>(kbuf, wkb, bk, Kh);
  gemm_bt<2><<<dim3(512), 256, 0, stream>>>(vbuf, wvb, bv, Vt);
  flash_attn<<<dim3(Bn * Hn * (Sn / 128)), 256, 0, stream>>>(Qh, Kh, Vt, Xb);
  gemm_bt<3><<<dim3(512), 256, 0, stream>>>(Xb, wob, bo, (float*)d_out);
}